// Round 10
// baseline (343.640 us; speedup 1.0000x reference)
//
#include <hip/hip_runtime.h>
#include <cstdint>

#define EMB 1024
#define HID 2048
#define BATCH 4
#define SEQ 2048
#define MROWS (BATCH * SEQ) /* 8192 */
#define N1 (3 * HID)        /* 6144 */
#define K1 EMB              /* 1024 */
#define N2 EMB              /* 1024 */
#define K2 HID              /* 2048 */

#define NX (MROWS * EMB)  /* 8388608 */
#define NW1 (N1 * K1)     /* 6291456 */
#define NW2 (N2 * K2)     /* 2097152 */

#define SEG 64            /* global time segments */
#define SLEN (SEQ / SEG)  /* 32 steps per segment */

typedef unsigned short ushort_t;
typedef __bf16 bf16x8 __attribute__((ext_vector_type(8)));
typedef float f32x4 __attribute__((ext_vector_type(4)));
typedef ushort_t us4 __attribute__((ext_vector_type(4)));

__device__ __forceinline__ ushort_t f2bf(float f) {
    uint32_t u = __builtin_bit_cast(uint32_t, f);
    u += 0x7fffu + ((u >> 16) & 1u);  // round-to-nearest-even
    return (ushort_t)(u >> 16);
}
__device__ __forceinline__ float bf2f(ushort_t h) {
    uint32_t u = ((uint32_t)h) << 16;
    return __builtin_bit_cast(float, u);
}
__device__ __forceinline__ float bflo(uint32_t v) {
    return __builtin_bit_cast(float, v << 16);
}
__device__ __forceinline__ float bfhi(uint32_t v) {
    return __builtin_bit_cast(float, v & 0xffff0000u);
}
__device__ __forceinline__ float sigm(float x) {
    return 1.f / (1.f + __expf(-x));
}

// async global->LDS, 16B per lane; LDS dest is wave-uniform base + lane*16
__device__ __forceinline__ void gload_lds16(const ushort_t* g, const ushort_t* l) {
    __builtin_amdgcn_global_load_lds(
        (const __attribute__((address_space(1))) void*)(uintptr_t)(g),
        (__attribute__((address_space(3))) void*)(uint32_t)(uintptr_t)(l),
        16, 0, 0);
}

// ---------------------------------------------------------------------------
// fp32 -> bf16 pre-convert of x, w1, w2
// ---------------------------------------------------------------------------
__global__ __launch_bounds__(256) void cvt_kernel(
    const float* __restrict__ x, const float* __restrict__ w1,
    const float* __restrict__ w2, ushort_t* __restrict__ xb,
    ushort_t* __restrict__ w1b, ushort_t* __restrict__ w2b) {
    const int i = (blockIdx.x * 256 + threadIdx.x) * 4;
    const float* s;
    ushort_t* d;
    if (i < NX) {
        s = x + i; d = xb + i;
    } else if (i < NX + NW1) {
        s = w1 + (i - NX); d = w1b + (i - NX);
    } else {
        s = w2 + (i - NX - NW1); d = w2b + (i - NX - NW1);
    }
    const float4 v = *(const float4*)s;
    us4 o;
    o.x = f2bf(v.x); o.y = f2bf(v.y); o.z = f2bf(v.z); o.w = f2bf(v.w);
    *(us4*)d = o;
}

// ---------------------------------------------------------------------------
// Shared fragment loader: [128 rows][64 k] LDS chunk, XOR-swizzled k-slots
// (LDS[row][slot] holds global k-slot slot^(row&7)); reads 4 frags x 2 slots.
// ---------------------------------------------------------------------------
__device__ __forceinline__ void lda4(bf16x8 (&af)[2][4], const ushort_t* c,
                                     int arow, int quad, int sw) {
#pragma unroll
    for (int s = 0; s < 2; ++s)
#pragma unroll
        for (int i = 0; i < 4; ++i)
            af[s][i] = *(const bf16x8*)&c[(arow + i * 16) * 64 +
                                          (((s * 4 + quad) ^ sw) << 3)];
}

// ---------------------------------------------------------------------------
// gemm_p (R10): 256(M)x128(N) / BK=64 / 8-wave / 3-buffer / DEPTH-3 staging /
// register double-buffered fragments / mid-window barrier. Serves BOTH GEMMs
// (template OUT dtype). C[M,N] = A[M,K]*B[N,K]^T, bf16 in, f32 acc.
//
// Mechanism (fixes the measured serialization: 5100cy/tile = 2483 MFMA +
// ~2050 LDS serial in R3): window T =
//   { reads(T+1) -> ALT reg set            (16 ds_read_b128)
//     [compiler lgkmcnt(16): reads(T) done, reads(T+1) stay outstanding]
//     MFMA(T) from CUR set                 (32 MFMA, reg-only)
//     BAR1   <- certifies reads(T) retired CHIP-WIDE
//     stage(T+3) -> buf T%3                (6 gload_lds, now-dead buffer)
//     vmcnt(6)  <- waits only stage(T+2) (issued one window ago)
//     BAR2 }
// LDS services reads(T+1) DURING MFMA(T); stage never overwrites a buffer
// with un-retired readers (BAR1 closes the 3-buffer depth-3 race).
//
// Certification ledger:
//  - reads(T+1) @T target buf (T+1)%3, staged @T-2; end-of-T-1 vmcnt(6)
//    forces stage(T+1) landed; BAR2(T-1) propagates.  SAFE.
//  - stage(T+3) @T targets buf T%3; readers = reads(T) issued @T-1, retired
//    at lgkm before MFMA(T), certified cross-wave by BAR1(T).  SAFE.
//  - vmcnt(6) leaves only stage(T+3) in flight; never drains hot loads.
// Prologue: stage 0,1,2; vmcnt(6) certifies tiles 0,1; read tile 0 -> X.
// Staging/read/epilogue mappings are gemm_mn's verified ones (R5/R7);
// K-order per output element ascending => outputs bit-identical.
// ---------------------------------------------------------------------------
template <bool OUT_BF16>
__global__ __launch_bounds__(512, 2) void gemm_p(
    const ushort_t* __restrict__ A, const ushort_t* __restrict__ B,
    void* __restrict__ Cv, int M, int N, int K) {
    __shared__ __align__(16) ushort_t sA[3][2][8192];  // 96 KB
    __shared__ __align__(16) ushort_t sB[3][8192];     // 48 KB

    const int tid  = threadIdx.x;
    const int lane = tid & 63;
    const int wave = tid >> 6;   // 0..7
    const int wm   = wave >> 1;  // 0..3 (64 rows each)
    const int wn   = wave & 1;   // 0..1 (64 cols each)
    const int quad = lane >> 4;
    const int l15  = lane & 15;
    const int sw   = lane & 7;

    // bijective XCD swizzle (nwg % 8 == 0 for both GEMMs)
    int wg = blockIdx.x;
    const int nwg = gridDim.x;
    if ((nwg & 7) == 0) wg = (wg & 7) * (nwg >> 3) + (wg >> 3);
    const int nbx = N >> 7;      // 128-col tiles
    const int bx = wg % nbx;
    const int by = wg / nbx;
    const long tm0 = (long)by << 8;   // 256-row tiles
    const long tn0 = (long)bx << 7;

    const ushort_t* gA = A + (size_t)tm0 * K;
    const ushort_t* gB = B + (size_t)tn0 * K;

    const int l8 = lane >> 3;
    const int ss = (lane & 7) ^ l8;   // inverse-swizzled source k-slot
    const uint32_t rA = (uint32_t)((wave & 3) * 16 + l8 + (wave >> 2) * 128);
    const uint32_t rB = (uint32_t)(wave * 16 + l8);
    const uint32_t offA0 = rA * (uint32_t)K + (uint32_t)ss * 8u;
    const uint32_t offA1 = offA0 + 8u * (uint32_t)K;
    const uint32_t offB0 = rB * (uint32_t)K + (uint32_t)ss * 8u;
    const uint32_t offB1 = offB0 + 8u * (uint32_t)K;

    const auto stA = [&](int tt, int q) {
        ushort_t* d = &sA[tt % 3][q][wave << 10];
        const size_t ko = (size_t)tt * 64 + (size_t)q * 64 * (size_t)K;
        gload_lds16(gA + ko + offA0, d);
        gload_lds16(gA + ko + offA1, d + 512);
    };
    const auto stB = [&](int tt) {
        ushort_t* d = &sB[tt % 3][wave << 10];
        const size_t ko = (size_t)tt * 64;
        gload_lds16(gB + ko + offB0, d);
        gload_lds16(gB + ko + offB1, d + 512);
    };

    const int cq   = wm & 1;                  // this wave's A chunk
    const int arow = (wm >> 1) * 64 + l15;    // local row base in chunk
    const int bcol = wn * 64 + l15;

    f32x4 acc[4][4] = {};
    bf16x8 afX[2][4], bfX[2][4], afY[2][4], bfY[2][4];

    const int NT = K >> 6;  // 16 (GEMM1) / 32 (GEMM2) tiles — even

    // prologue: stage tiles 0,1,2; vmcnt(6) certifies tiles 0 AND 1
    // (leaves tile 2's 6 loads in flight); read tile 0 into set X.
    stA(0, 0); stA(0, 1); stB(0);
    stA(1, 0); stA(1, 1); stB(1);
    stA(2, 0); stA(2, 1); stB(2);
    asm volatile("s_waitcnt vmcnt(6)" ::: "memory");
    __builtin_amdgcn_s_barrier();
    lda4(afX, &sA[0][cq][0], arow, quad, sw);
    lda4(bfX, &sB[0][0],     bcol, quad, sw);

    const auto body = [&](int T, bf16x8 (&ca)[2][4], bf16x8 (&cb)[2][4],
                                 bf16x8 (&na)[2][4], bf16x8 (&nb)[2][4]) {
        // reads(T+1) FIRST — LDS serves them while MFMA(T) executes
        if (T + 1 < NT) {
            const int ib = (T + 1) % 3;
            lda4(na, &sA[ib][cq][0], arow, quad, sw);
            lda4(nb, &sB[ib][0],     bcol, quad, sw);
        }
        __builtin_amdgcn_s_setprio(1);
#pragma unroll
        for (int s = 0; s < 2; ++s)
#pragma unroll
            for (int i = 0; i < 4; ++i)
#pragma unroll
                for (int j = 0; j < 4; ++j)
                    acc[i][j] = __builtin_amdgcn_mfma_f32_16x16x32_bf16(
                        ca[s][i], cb[s][j], acc[i][j], 0, 0, 0);
        __builtin_amdgcn_s_setprio(0);
        __builtin_amdgcn_s_barrier();   // BAR1: reads(T) retired chip-wide
        if (T + 3 < NT) {
            stA(T + 3, 0); stA(T + 3, 1); stB(T + 3);
            asm volatile("s_waitcnt vmcnt(6)" ::: "memory");
        } else {
            asm volatile("s_waitcnt vmcnt(0)" ::: "memory");  // stale only
        }
        __builtin_amdgcn_s_barrier();   // BAR2
    };

    for (int T = 0; T < NT; T += 2) {
        body(T,     afX, bfX, afY, bfY);
        body(T + 1, afY, bfY, afX, bfX);
    }

    // epilogue: C/D layout col=lane&15, row=quad*4+reg
#pragma unroll
    for (int i = 0; i < 4; ++i) {
        const long row0 = tm0 + wm * 64 + i * 16 + quad * 4;
#pragma unroll
        for (int j = 0; j < 4; ++j) {
            const long col = tn0 + wn * 64 + j * 16 + l15;
#pragma unroll
            for (int r = 0; r < 4; ++r) {
                if constexpr (OUT_BF16) {
                    ((ushort_t*)Cv)[(size_t)(row0 + r) * N + col] = f2bf(acc[i][j][r]);
                } else {
                    ((float*)Cv)[(size_t)(row0 + r) * N + col] = acc[i][j][r];
                }
            }
        }
    }
}

// ---------------------------------------------------------------------------
// Segmented scan, 3 kernels (SEG=64, 4 blocks/CU — R7, verified).
// NOTE: do NOT hold the streams in large register arrays across phases —
// the compiler demotes >~32-dword locals to scratch. Re-read via L3.
// ---------------------------------------------------------------------------
__global__ __launch_bounds__(256) void scan_part1(
    const ushort_t* __restrict__ y, const float* __restrict__ cw,
    float* __restrict__ Ag, float* __restrict__ Bg) {
    const int gid = blockIdx.x * 256 + threadIdx.x;
    const int ch  = (gid & 1023) * 2;
    const int bs  = gid >> 10;
    const int b   = bs >> 6;
    const int seg = bs & 63;
    const int t0  = seg * SLEN;
    const size_t rowbase = (size_t)b * SEQ;
    const ushort_t* yz = y + 2048 + ch;
    const ushort_t* yh = y + 4096 + ch;

    float w[2][4];
#pragma unroll
    for (int c = 0; c < 2; ++c)
#pragma unroll
        for (int k = 0; k < 4; ++k) w[c][k] = cw[(ch + c) * 4 + k];

    auto ld2 = [&](const ushort_t* p, int t) -> uint32_t {
        return *(const uint32_t*)(p + (rowbase + (size_t)t) * 6144);
    };
    auto zpair = [&](int t, float* out) {
        if (t < 0) { out[0] = 0.f; out[1] = 0.f; }
        else { uint32_t v = ld2(yz, t); out[0] = bflo(v); out[1] = bfhi(v); }
    };

    float z1[2], z2[2], z3[2], A[2] = {1.f, 1.f}, Bv[2] = {0.f, 0.f};
    zpair(t0 - 1, z1); zpair(t0 - 2, z2); zpair(t0 - 3, z3);

#pragma unroll 8
    for (int t = t0; t < t0 + SLEN; ++t) {
        const uint32_t vz = ld2(yz, t);
        const uint32_t vh = ld2(yh, t);
        const float zr[2] = {bflo(vz), bfhi(vz)};
        const float hr[2] = {bflo(vh), bfhi(vh)};
#pragma unroll
        for (int c = 0; c < 2; ++c) {
            const float cv = w[c][0] * z3[c] + w[c][1] * z2[c] +
                             w[c][2] * z1[c] + w[c][3] * zr[c];
            const float s = sigm(cv);
            z3[c] = z2[c]; z2[c] = z1[c]; z1[c] = zr[c];
            const float a = 1.f - s;
            A[c] *= a;
            Bv[c] = a * Bv[c] + s * hr[c];
        }
    }
    const size_t idx = ((size_t)b * SEG + seg) * HID + ch;
    *(float2*)&Ag[idx] = make_float2(A[0], A[1]);
    *(float2*)&Bg[idx] = make_float2(Bv[0], Bv[1]);
}

// one thread per (b, ch): serial exclusive combine over SEG segments
__global__ __launch_bounds__(256) void scan_part2(
    const float* __restrict__ Ag, const float* __restrict__ Bg,
    float* __restrict__ Cr) {
    const int gid = blockIdx.x * 256 + threadIdx.x;  // [0, 8192)
    const int b  = gid >> 11;
    const int ch = gid & 2047;
    float carry = 0.f;
#pragma unroll
    for (int s = 0; s < SEG; ++s) {
        const size_t idx = ((size_t)b * SEG + s) * HID + ch;
        Cr[idx] = carry;
        carry = Ag[idx] * carry + Bg[idx];
    }
}

__global__ __launch_bounds__(256) void scan_part3(
    const ushort_t* __restrict__ y, const float* __restrict__ cw,
    const float* __restrict__ Cr, ushort_t* __restrict__ u) {
    const int gid = blockIdx.x * 256 + threadIdx.x;
    const int ch  = (gid & 1023) * 2;
    const int bs  = gid >> 10;
    const int b   = bs >> 6;
    const int seg = bs & 63;
    const int t0  = seg * SLEN;
    const size_t rowbase = (size_t)b * SEQ;
    const ushort_t* yo = y + ch;
    const ushort_t* yz = y + 2048 + ch;
    const ushort_t* yh = y + 4096 + ch;

    float w[2][4];
#pragma unroll
    for (int c = 0; c < 2; ++c)
#pragma unroll
        for (int k = 0; k < 4; ++k) w[c][k] = cw[(ch + c) * 4 + k];

    auto ld2 = [&](const ushort_t* p, int t) -> uint32_t {
        return *(const uint32_t*)(p + (rowbase + (size_t)t) * 6144);
    };
    auto zpair = [&](int t, float* out) {
        if (t < 0) { out[0] = 0.f; out[1] = 0.f; }
        else { uint32_t v = ld2(yz, t); out[0] = bflo(v); out[1] = bfhi(v); }
    };

    const size_t cidx = ((size_t)b * SEG + seg) * HID + ch;
    float h[2] = {Cr[cidx], Cr[cidx + 1]};
    float z1[2], z2[2], z3[2];
    zpair(t0 - 1, z1); zpair(t0 - 2, z2); zpair(t0 - 3, z3);

#pragma unroll 8
    for (int t = t0; t < t0 + SLEN; ++t) {
        const uint32_t vz = ld2(yz, t);
        const uint32_t vh = ld2(yh, t);
        const uint32_t vo = ld2(yo, t);
        const float zr[2] = {bflo(vz), bfhi(vz)};
        const float hr[2] = {bflo(vh), bfhi(vh)};
        const float o1[2] = {bflo(vo), bfhi(vo)};
        ushort_t res[2];
#pragma unroll
        for (int c = 0; c < 2; ++c) {
            const float cv = w[c][0] * z3[c] + w[c][1] * z2[c] +
                             w[c][2] * z1[c] + w[c][3] * zr[c];
            const float s = sigm(cv);
            z3[c] = z2[c]; z2[c] = z1[c]; z1[c] = zr[c];
            h[c] = (1.f - s) * h[c] + s * hr[c];
            const float sil = o1[c] * sigm(o1[c]);
            res[c] = f2bf(sil * h[c]);
        }
        *(uint32_t*)&u[(rowbase + (size_t)t) * (size_t)HID + ch] =
            (uint32_t)res[0] | ((uint32_t)res[1] << 16);
    }
}

// ---------------------------------------------------------------------------
extern "C" void kernel_launch(void* const* d_in, const int* in_sizes, int n_in,
                              void* d_out, int out_size, void* d_ws, size_t ws_size,
                              hipStream_t stream) {
    const float* x  = (const float*)d_in[0];
    const float* w1 = (const float*)d_in[1];
    const float* w2 = (const float*)d_in[2];
    const float* cw = (const float*)d_in[3];
    char* ws = (char*)d_ws;

    // ws layout (bytes): xb 16MiB | w1b 12MiB | w2b 4MiB | y 96MiB | u 32MiB = 160MiB
    ushort_t* xb  = (ushort_t*)(ws);
    ushort_t* w1b = (ushort_t*)(ws + (size_t)16777216);
    ushort_t* w2b = (ushort_t*)(ws + (size_t)29360128);
    ushort_t* y   = (ushort_t*)(ws + (size_t)33554432);
    ushort_t* u   = (ushort_t*)(ws + (size_t)134217728);
    // scan scratch reuses the xb region (dead after GEMM1): 3 x 2 MiB fp32
    float* Ag = (float*)(ws);
    float* Bg = (float*)(ws + (size_t)2097152);
    float* Cr = (float*)(ws + (size_t)4194304);
    float* out = (float*)d_out;

    cvt_kernel<<<16384, 256, 0, stream>>>(x, w1, w2, xb, w1b, w2b);
    // GEMM1: pipelined 256x128 kernel, grid = 48*32 = 1536 (bf16 out -> y)
    gemm_p<true><<<dim3(1536), 512, 0, stream>>>(xb, w1b, (void*)y, MROWS, N1, K1);
    // scans at SEG=64: 1024 blocks = 4 blocks/CU
    scan_part1<<<1024, 256, 0, stream>>>(y, cw, Ag, Bg);
    scan_part2<<<32, 256, 0, stream>>>(Ag, Bg, Cr);
    scan_part3<<<1024, 256, 0, stream>>>(y, cw, Cr, u);
    // GEMM2: same pipelined kernel, grid = 8*32 = 256 (f32 out)
    gemm_p<false><<<dim3(256), 512, 0, stream>>>(u, w2b, (void*)out, MROWS, N2, K2);
}

// Round 12
// 303.390 us; speedup vs baseline: 1.1327x; 1.1327x over previous
//
#include <hip/hip_runtime.h>
#include <cstdint>

#define EMB 1024
#define HID 2048
#define BATCH 4
#define SEQ 2048
#define MROWS (BATCH * SEQ) /* 8192 */
#define N1 (3 * HID)        /* 6144 */
#define K1 EMB              /* 1024 */
#define N2 EMB              /* 1024 */
#define K2 HID              /* 2048 */

#define NX (MROWS * EMB)  /* 8388608 */
#define NW1 (N1 * K1)     /* 6291456 */
#define NW2 (N2 * K2)     /* 2097152 */

#define SEG 128           /* global time segments (R11: 64->128, 8 blocks/CU) */
#define SLEN (SEQ / SEG)  /* 16 steps per segment */

typedef unsigned short ushort_t;
typedef __bf16 bf16x8 __attribute__((ext_vector_type(8)));
typedef float f32x4 __attribute__((ext_vector_type(4)));
typedef ushort_t us4 __attribute__((ext_vector_type(4)));

__device__ __forceinline__ ushort_t f2bf(float f) {
    uint32_t u = __builtin_bit_cast(uint32_t, f);
    u += 0x7fffu + ((u >> 16) & 1u);  // round-to-nearest-even
    return (ushort_t)(u >> 16);
}
__device__ __forceinline__ float bf2f(ushort_t h) {
    uint32_t u = ((uint32_t)h) << 16;
    return __builtin_bit_cast(float, u);
}
__device__ __forceinline__ float bflo(uint32_t v) {
    return __builtin_bit_cast(float, v << 16);
}
__device__ __forceinline__ float bfhi(uint32_t v) {
    return __builtin_bit_cast(float, v & 0xffff0000u);
}
__device__ __forceinline__ float sigm(float x) {
    return 1.f / (1.f + __expf(-x));
}

// async global->LDS, 16B per lane; LDS dest is wave-uniform base + lane*16
__device__ __forceinline__ void gload_lds16(const ushort_t* g, const ushort_t* l) {
    __builtin_amdgcn_global_load_lds(
        (const __attribute__((address_space(1))) void*)(uintptr_t)(g),
        (__attribute__((address_space(3))) void*)(uint32_t)(uintptr_t)(l),
        16, 0, 0);
}

// ---------------------------------------------------------------------------
// fp32 -> bf16 pre-convert of x, w1, w2
// ---------------------------------------------------------------------------
__global__ __launch_bounds__(256) void cvt_kernel(
    const float* __restrict__ x, const float* __restrict__ w1,
    const float* __restrict__ w2, ushort_t* __restrict__ xb,
    ushort_t* __restrict__ w1b, ushort_t* __restrict__ w2b) {
    const int i = (blockIdx.x * 256 + threadIdx.x) * 4;
    const float* s;
    ushort_t* d;
    if (i < NX) {
        s = x + i; d = xb + i;
    } else if (i < NX + NW1) {
        s = w1 + (i - NX); d = w1b + (i - NX);
    } else {
        s = w2 + (i - NX - NW1); d = w2b + (i - NX - NW1);
    }
    const float4 v = *(const float4*)s;
    us4 o;
    o.x = f2bf(v.x); o.y = f2bf(v.y); o.z = f2bf(v.z); o.w = f2bf(v.w);
    *(us4*)d = o;
}

// ---------------------------------------------------------------------------
// Shared fragment loader: [128 rows][64 k] LDS chunk, XOR-swizzled k-slots
// (LDS[row][slot] holds global k-slot slot^(row&7)); reads 4 frags x 2 slots.
// ---------------------------------------------------------------------------
__device__ __forceinline__ void lda4(bf16x8 (&af)[2][4], const ushort_t* c,
                                     int arow, int quad, int sw) {
#pragma unroll
    for (int s = 0; s < 2; ++s)
#pragma unroll
        for (int i = 0; i < 4; ++i)
            af[s][i] = *(const bf16x8*)&c[(arow + i * 16) * 64 +
                                          (((s * 4 + quad) ^ sw) << 3)];
}
__device__ __forceinline__ void ldb2(bf16x8 (&bfr)[2][2], const ushort_t* c,
                                     int bcol, int quad, int sw) {
#pragma unroll
    for (int s = 0; s < 2; ++s)
#pragma unroll
        for (int j = 0; j < 2; ++j)
            bfr[s][j] = *(const bf16x8*)&c[(bcol + j * 16) * 64 +
                                           (((s * 4 + quad) ^ sw) << 3)];
}
template <int QM, int QN>
__device__ __forceinline__ void mm16(f32x4 (&acc)[8][4],
                                     const bf16x8 (&af)[2][4],
                                     const bf16x8 (&bfr)[2][2]) {
#pragma unroll
    for (int s = 0; s < 2; ++s)
#pragma unroll
        for (int i = 0; i < 4; ++i)
#pragma unroll
            for (int j = 0; j < 2; ++j)
                acc[QM * 4 + i][QN * 2 + j] =
                    __builtin_amdgcn_mfma_f32_16x16x32_bf16(
                        af[s][i], bfr[s][j], acc[QM * 4 + i][QN * 2 + j], 0, 0, 0);
}

// ---------------------------------------------------------------------------
// GEMM1: 256x256 / BK=64 / 8-wave, ONE barrier per K-tile (R3, verified
// 101.5us / ~1016 TF, MfmaUtil 44%). Six K-loop structures tried (R1 8-phase,
// R2 3-phase-reg, R3 1-barrier, R8 BK=32 depth-3, R10 256x128 depth-3):
// R3 wins. 128KB LDS => 1 block/CU; the ~44% cap is the intra-window
// first-read drain. Do NOT restructure without new counter evidence.
// ---------------------------------------------------------------------------
template <bool OUT_BF16>
__global__ __launch_bounds__(512, 2) void gemm256(
    const ushort_t* __restrict__ A, const ushort_t* __restrict__ B,
    void* __restrict__ Cv, int M, int N, int K) {
    __shared__ __align__(16) ushort_t sA[2][2][8192];
    __shared__ __align__(16) ushort_t sB[2][2][8192];

    const int tid  = threadIdx.x;
    const int lane = tid & 63;
    const int wave = tid >> 6;   // 0..7
    const int wm   = wave >> 2;  // 0..1
    const int wn   = wave & 3;   // 0..3
    const int quad = lane >> 4;
    const int l15  = lane & 15;
    const int sw   = lane & 7;   // row&7 for fragment rows

    // bijective XCD swizzle (nwg % 8 == 0 for our shapes)
    int wg = blockIdx.x;
    const int nwg = gridDim.x;
    if ((nwg & 7) == 0) wg = (wg & 7) * (nwg >> 3) + (wg >> 3);
    const int nbx = N >> 8;
    const int bx = wg % nbx;
    const int by = wg / nbx;
    const long tm0 = (long)by << 8;
    const long tn0 = (long)bx << 8;

    const ushort_t* gA = A + (size_t)tm0 * K;
    const ushort_t* gB = B + (size_t)tn0 * K;

    // staging per-lane source offsets (elements), inverse-swizzled k-slot
    const int l8 = lane >> 3;                 // = dest row & 7
    const int ss = (lane & 7) ^ l8;           // source k-slot
    const uint32_t rA = (uint32_t)((wave & 3) * 16 + l8 + (wave >> 2) * 128);
    const int cB = wave * 16 + l8;            // chunk-local col (strip-safe)
    const uint32_t rB = (uint32_t)((cB >> 5) * 64 + (cB & 31));
    const uint32_t offA0 = rA * (uint32_t)K + (uint32_t)ss * 8u;
    const uint32_t offA1 = offA0 + 8u * (uint32_t)K;
    const uint32_t offB0 = rB * (uint32_t)K + (uint32_t)ss * 8u;
    const uint32_t offB1 = offB0 + 8u * (uint32_t)K;

    const auto stA = [&](int tt, int q) {
        ushort_t* d = &sA[tt & 1][q][wave << 10];
        const size_t ko = (size_t)tt * 64 + (size_t)q * 64 * (size_t)K;
        gload_lds16(gA + ko + offA0, d);
        gload_lds16(gA + ko + offA1, d + 512);
    };
    const auto stB = [&](int tt, int q) {
        ushort_t* d = &sB[tt & 1][q][wave << 10];
        const size_t ko = (size_t)tt * 64 + (size_t)q * 32 * (size_t)K;
        gload_lds16(gB + ko + offB0, d);
        gload_lds16(gB + ko + offB1, d + 512);
    };

    const int arow = wm * 64 + l15;
    const int bcol = wn * 32 + l15;

    f32x4 acc[8][4] = {};
    bf16x8 af0[2][4], af1[2][4], bf0[2][2], bf1[2][2];

    const int NT = K >> 6;  // K-tiles

    // prologue: stage tile 0 fully, drain, barrier.
    stA(0, 0); stB(0, 0); stB(0, 1); stA(0, 1);
    asm volatile("s_waitcnt vmcnt(0)" ::: "memory");
    __builtin_amdgcn_s_barrier();

    for (int T = 0; T < NT; ++T) {
        const int cur = T & 1;
        const ushort_t* a0 = &sA[cur][0][0];
        const ushort_t* a1 = &sA[cur][1][0];
        const ushort_t* b0 = &sB[cur][0][0];
        const ushort_t* b1 = &sB[cur][1][0];
        const bool st1 = (T + 1 < NT);

        // all 24 ds_reads first (operand waits can never alias staging)
        lda4(af0, a0, arow, quad, sw);
        ldb2(bf0, b0, bcol, quad, sw);
        ldb2(bf1, b1, bcol, quad, sw);
        lda4(af1, a1, arow, quad, sw);
        // all 8 stages for tile T+1 into the other (dead) buffer
        if (st1) {
            stA(T + 1, 0); stB(T + 1, 0);
            stB(T + 1, 1); stA(T + 1, 1);
        }
        // 64 MFMA; compiler waits lgkm counted per operand cluster, so
        // reads 13..24 land under mm<0,0>'s execution.
        __builtin_amdgcn_s_setprio(1);
        mm16<0, 0>(acc, af0, bf0);
        mm16<0, 1>(acc, af0, bf1);
        mm16<1, 0>(acc, af1, bf0);
        mm16<1, 1>(acc, af1, bf1);
        __builtin_amdgcn_s_setprio(0);
        // drain this tile's stages (issued ~one MFMA-cluster ago => stale)
        if (st1) asm volatile("s_waitcnt vmcnt(0)" ::: "memory");
        __builtin_amdgcn_s_barrier();
    }

    // epilogue: C/D layout col=lane&15, row=quad*4+reg
#pragma unroll
    for (int ai = 0; ai < 8; ++ai) {
        const long row0 = tm0 + wm * 128 + (ai >> 2) * 64 + (ai & 3) * 16 + quad * 4;
#pragma unroll
        for (int bj = 0; bj < 4; ++bj) {
            const long col = tn0 + wn * 64 + (bj >> 1) * 32 + (bj & 1) * 16 + l15;
#pragma unroll
            for (int r = 0; r < 4; ++r) {
                if constexpr (OUT_BF16) {
                    ((ushort_t*)Cv)[(size_t)(row0 + r) * N + col] = f2bf(acc[ai][bj][r]);
                } else {
                    ((float*)Cv)[(size_t)(row0 + r) * N + col] = acc[ai][bj][r];
                }
            }
        }
    }
}

// ---------------------------------------------------------------------------
// GEMM2: 256(M)x128(N) / BK=64 / 8-wave, triple-buffered, counted vmcnt(6),
// 2-tile prefetch (R7, best-verified GEMM2). R9's 128^2/2-block variant
// regressed +13us (more staging traffic, no cross-block overlap) — reverted.
// ---------------------------------------------------------------------------
__global__ __launch_bounds__(512, 1) void gemm_mn(
    const ushort_t* __restrict__ A, const ushort_t* __restrict__ B,
    float* __restrict__ C, int M, int N, int K) {
    __shared__ __align__(16) ushort_t sA[3][2][8192];
    __shared__ __align__(16) ushort_t sB[3][8192];

    const int tid  = threadIdx.x;
    const int lane = tid & 63;
    const int wave = tid >> 6;   // 0..7
    const int wm   = wave >> 1;  // 0..3
    const int wn   = wave & 1;   // 0..1
    const int quad = lane >> 4;
    const int l15  = lane & 15;
    const int sw   = lane & 7;

    // bijective XCD swizzle (256 % 8 == 0)
    int wg = blockIdx.x;
    const int nwg = gridDim.x;
    if ((nwg & 7) == 0) wg = (wg & 7) * (nwg >> 3) + (wg >> 3);
    const int nbx = N >> 7;      // 128-col tiles
    const int bx = wg % nbx;
    const int by = wg / nbx;
    const long tm0 = (long)by << 8;   // 256-row tiles
    const long tn0 = (long)bx << 7;

    const ushort_t* gA = A + (size_t)tm0 * K;
    const ushort_t* gB = B + (size_t)tn0 * K;

    const int l8 = lane >> 3;
    const int ss = (lane & 7) ^ l8;
    const uint32_t rA = (uint32_t)((wave & 3) * 16 + l8 + (wave >> 2) * 128);
    const uint32_t rB = (uint32_t)(wave * 16 + l8);
    const uint32_t offA0 = rA * (uint32_t)K + (uint32_t)ss * 8u;
    const uint32_t offA1 = offA0 + 8u * (uint32_t)K;
    const uint32_t offB0 = rB * (uint32_t)K + (uint32_t)ss * 8u;
    const uint32_t offB1 = offB0 + 8u * (uint32_t)K;

    const auto stA = [&](int tt, int q) {
        ushort_t* d = &sA[tt % 3][q][wave << 10];
        const size_t ko = (size_t)tt * 64 + (size_t)q * 64 * (size_t)K;
        gload_lds16(gA + ko + offA0, d);
        gload_lds16(gA + ko + offA1, d + 512);
    };
    const auto stB = [&](int tt) {
        ushort_t* d = &sB[tt % 3][wave << 10];
        const size_t ko = (size_t)tt * 64;
        gload_lds16(gB + ko + offB0, d);
        gload_lds16(gB + ko + offB1, d + 512);
    };

    const int cq   = wm & 1;                  // this wave's A chunk
    const int arow = (wm >> 1) * 64 + l15;    // local row base in chunk
    const int bcol = wn * 64 + l15;

    f32x4 acc[4][4] = {};
    bf16x8 af[2][4], bf[2][4];

    const int NT = K >> 6;  // 32 tiles

    stA(0, 0); stA(0, 1); stB(0);
    stA(1, 0); stA(1, 1); stB(1);
    asm volatile("s_waitcnt vmcnt(6)" ::: "memory");
    __builtin_amdgcn_s_barrier();

    for (int T = 0; T < NT; ++T) {
        const int cur = T % 3;
        const ushort_t* pa = &sA[cur][cq][0];
        const ushort_t* pb = &sB[cur][0];
        const bool st2 = (T + 2 < NT);

        lda4(af, pa, arow, quad, sw);
        lda4(bf, pb, bcol, quad, sw);
        if (st2) { stA(T + 2, 0); stA(T + 2, 1); stB(T + 2); }
        __builtin_amdgcn_s_setprio(1);
#pragma unroll
        for (int s = 0; s < 2; ++s)
#pragma unroll
            for (int i = 0; i < 4; ++i)
#pragma unroll
                for (int j = 0; j < 4; ++j)
                    acc[i][j] = __builtin_amdgcn_mfma_f32_16x16x32_bf16(
                        af[s][i], bf[s][j], acc[i][j], 0, 0, 0);
        __builtin_amdgcn_s_setprio(0);
        if (st2)                asm volatile("s_waitcnt vmcnt(6)" ::: "memory");
        else if (T + 1 < NT)    asm volatile("s_waitcnt vmcnt(0)" ::: "memory");
        __builtin_amdgcn_s_barrier();
    }

#pragma unroll
    for (int i = 0; i < 4; ++i) {
        const long row0 = tm0 + wm * 64 + i * 16 + quad * 4;
#pragma unroll
        for (int j = 0; j < 4; ++j) {
            const long col = tn0 + wn * 64 + j * 16 + l15;
#pragma unroll
            for (int r = 0; r < 4; ++r)
                C[(size_t)(row0 + r) * N + col] = acc[i][j][r];
        }
    }
}

// ---------------------------------------------------------------------------
// Segmented scan, 3 kernels. R11: SEG 64->128 (part1/3 grid 2048 blocks =
// 8 blocks/CU = 32 waves/CU, full occupancy) — the strided-4B loads are
// latency-bound; max TLP hides it. part2: 128 serial steps (trivial).
// NOTE: do NOT hold the streams in large register arrays across phases —
// the compiler demotes >~32-dword locals to scratch. Re-read via L3.
// ---------------------------------------------------------------------------
__global__ __launch_bounds__(256) void scan_part1(
    const ushort_t* __restrict__ y, const float* __restrict__ cw,
    float* __restrict__ Ag, float* __restrict__ Bg) {
    const int gid = blockIdx.x * 256 + threadIdx.x;
    const int ch  = (gid & 1023) * 2;
    const int bs  = gid >> 10;          // [0, BATCH*SEG)
    const int b   = bs >> 7;
    const int seg = bs & 127;
    const int t0  = seg * SLEN;
    const size_t rowbase = (size_t)b * SEQ;
    const ushort_t* yz = y + 2048 + ch;
    const ushort_t* yh = y + 4096 + ch;

    float w[2][4];
#pragma unroll
    for (int c = 0; c < 2; ++c)
#pragma unroll
        for (int k = 0; k < 4; ++k) w[c][k] = cw[(ch + c) * 4 + k];

    auto ld2 = [&](const ushort_t* p, int t) -> uint32_t {
        return *(const uint32_t*)(p + (rowbase + (size_t)t) * 6144);
    };
    auto zpair = [&](int t, float* out) {
        if (t < 0) { out[0] = 0.f; out[1] = 0.f; }
        else { uint32_t v = ld2(yz, t); out[0] = bflo(v); out[1] = bfhi(v); }
    };

    float z1[2], z2[2], z3[2], A[2] = {1.f, 1.f}, Bv[2] = {0.f, 0.f};
    zpair(t0 - 1, z1); zpair(t0 - 2, z2); zpair(t0 - 3, z3);

#pragma unroll 8
    for (int t = t0; t < t0 + SLEN; ++t) {
        const uint32_t vz = ld2(yz, t);
        const uint32_t vh = ld2(yh, t);
        const float zr[2] = {bflo(vz), bfhi(vz)};
        const float hr[2] = {bflo(vh), bfhi(vh)};
#pragma unroll
        for (int c = 0; c < 2; ++c) {
            const float cv = w[c][0] * z3[c] + w[c][1] * z2[c] +
                             w[c][2] * z1[c] + w[c][3] * zr[c];
            const float s = sigm(cv);
            z3[c] = z2[c]; z2[c] = z1[c]; z1[c] = zr[c];
            const float a = 1.f - s;
            A[c] *= a;
            Bv[c] = a * Bv[c] + s * hr[c];
        }
    }
    const size_t idx = ((size_t)b * SEG + seg) * HID + ch;
    *(float2*)&Ag[idx] = make_float2(A[0], A[1]);
    *(float2*)&Bg[idx] = make_float2(Bv[0], Bv[1]);
}

// one thread per (b, ch): serial exclusive combine over SEG segments
__global__ __launch_bounds__(256) void scan_part2(
    const float* __restrict__ Ag, const float* __restrict__ Bg,
    float* __restrict__ Cr) {
    const int gid = blockIdx.x * 256 + threadIdx.x;  // [0, 8192)
    const int b  = gid >> 11;
    const int ch = gid & 2047;
    float carry = 0.f;
#pragma unroll 8
    for (int s = 0; s < SEG; ++s) {
        const size_t idx = ((size_t)b * SEG + s) * HID + ch;
        Cr[idx] = carry;
        carry = Ag[idx] * carry + Bg[idx];
    }
}

__global__ __launch_bounds__(256) void scan_part3(
    const ushort_t* __restrict__ y, const float* __restrict__ cw,
    const float* __restrict__ Cr, ushort_t* __restrict__ u) {
    const int gid = blockIdx.x * 256 + threadIdx.x;
    const int ch  = (gid & 1023) * 2;
    const int bs  = gid >> 10;
    const int b   = bs >> 7;
    const int seg = bs & 127;
    const int t0  = seg * SLEN;
    const size_t rowbase = (size_t)b * SEQ;
    const ushort_t* yo = y + ch;
    const ushort_t* yz = y + 2048 + ch;
    const ushort_t* yh = y + 4096 + ch;

    float w[2][4];
#pragma unroll
    for (int c = 0; c < 2; ++c)
#pragma unroll
        for (int k = 0; k < 4; ++k) w[c][k] = cw[(ch + c) * 4 + k];

    auto ld2 = [&](const ushort_t* p, int t) -> uint32_t {
        return *(const uint32_t*)(p + (rowbase + (size_t)t) * 6144);
    };
    auto zpair = [&](int t, float* out) {
        if (t < 0) { out[0] = 0.f; out[1] = 0.f; }
        else { uint32_t v = ld2(yz, t); out[0] = bflo(v); out[1] = bfhi(v); }
    };

    const size_t cidx = ((size_t)b * SEG + seg) * HID + ch;
    float h[2] = {Cr[cidx], Cr[cidx + 1]};
    float z1[2], z2[2], z3[2];
    zpair(t0 - 1, z1); zpair(t0 - 2, z2); zpair(t0 - 3, z3);

#pragma unroll 8
    for (int t = t0; t < t0 + SLEN; ++t) {
        const uint32_t vz = ld2(yz, t);
        const uint32_t vh = ld2(yh, t);
        const uint32_t vo = ld2(yo, t);
        const float zr[2] = {bflo(vz), bfhi(vz)};
        const float hr[2] = {bflo(vh), bfhi(vh)};
        const float o1[2] = {bflo(vo), bfhi(vo)};
        ushort_t res[2];
#pragma unroll
        for (int c = 0; c < 2; ++c) {
            const float cv = w[c][0] * z3[c] + w[c][1] * z2[c] +
                             w[c][2] * z1[c] + w[c][3] * zr[c];
            const float s = sigm(cv);
            z3[c] = z2[c]; z2[c] = z1[c]; z1[c] = zr[c];
            h[c] = (1.f - s) * h[c] + s * hr[c];
            const float sil = o1[c] * sigm(o1[c]);
            res[c] = f2bf(sil * h[c]);
        }
        *(uint32_t*)&u[(rowbase + (size_t)t) * (size_t)HID + ch] =
            (uint32_t)res[0] | ((uint32_t)res[1] << 16);
    }
}

// ---------------------------------------------------------------------------
extern "C" void kernel_launch(void* const* d_in, const int* in_sizes, int n_in,
                              void* d_out, int out_size, void* d_ws, size_t ws_size,
                              hipStream_t stream) {
    const float* x  = (const float*)d_in[0];
    const float* w1 = (const float*)d_in[1];
    const float* w2 = (const float*)d_in[2];
    const float* cw = (const float*)d_in[3];
    char* ws = (char*)d_ws;

    // ws layout (bytes): xb 16MiB | w1b 12MiB | w2b 4MiB | y 96MiB | u 32MiB = 160MiB
    ushort_t* xb  = (ushort_t*)(ws);
    ushort_t* w1b = (ushort_t*)(ws + (size_t)16777216);
    ushort_t* w2b = (ushort_t*)(ws + (size_t)29360128);
    ushort_t* y   = (ushort_t*)(ws + (size_t)33554432);
    ushort_t* u   = (ushort_t*)(ws + (size_t)134217728);
    // scan scratch reuses the xb region (dead after GEMM1): 3 x 4 MiB fp32
    float* Ag = (float*)(ws);
    float* Bg = (float*)(ws + (size_t)4194304);
    float* Cr = (float*)(ws + (size_t)8388608);
    float* out = (float*)d_out;

    cvt_kernel<<<16384, 256, 0, stream>>>(x, w1, w2, xb, w1b, w2b);
    // GEMM1: 256^2 single-barrier de-phased kernel (R3), grid = 32*24 = 768
    gemm256<true><<<dim3(768), 512, 0, stream>>>(xb, w1b, (void*)y, MROWS, N1, K1);
    // scans at SEG=128: 2048 blocks = 8 blocks/CU (full wave occupancy)
    scan_part1<<<2048, 256, 0, stream>>>(y, cw, Ag, Bg);
    scan_part2<<<32, 256, 0, stream>>>(Ag, Bg, Cr);
    scan_part3<<<2048, 256, 0, stream>>>(y, cw, Cr, u);
    // GEMM2: 256x128-tile triple-buffered kernel (R7), grid = 32*8 = 256
    gemm_mn<<<dim3(256), 512, 0, stream>>>(u, w2b, out, MROWS, N2, K2);
}

// Round 13
// 286.156 us; speedup vs baseline: 1.2009x; 1.0602x over previous
//
#include <hip/hip_runtime.h>
#include <cstdint>

#define EMB 1024
#define HID 2048
#define BATCH 4
#define SEQ 2048
#define MROWS (BATCH * SEQ) /* 8192 */
#define N1 (3 * HID)        /* 6144 */
#define K1 EMB              /* 1024 */
#define N2 EMB              /* 1024 */
#define K2 HID              /* 2048 */

#define NX (MROWS * EMB)  /* 8388608 */
#define NW1 (N1 * K1)     /* 6291456 */
#define NW2 (N2 * K2)     /* 2097152 */

#define SEG 64            /* global time segments — swept {32,64,128}: 64 optimal */
#define SLEN (SEQ / SEG)  /* 32 steps per segment */

typedef unsigned short ushort_t;
typedef __bf16 bf16x8 __attribute__((ext_vector_type(8)));
typedef float f32x4 __attribute__((ext_vector_type(4)));
typedef ushort_t us4 __attribute__((ext_vector_type(4)));

__device__ __forceinline__ ushort_t f2bf(float f) {
    uint32_t u = __builtin_bit_cast(uint32_t, f);
    u += 0x7fffu + ((u >> 16) & 1u);  // round-to-nearest-even
    return (ushort_t)(u >> 16);
}
__device__ __forceinline__ float bf2f(ushort_t h) {
    uint32_t u = ((uint32_t)h) << 16;
    return __builtin_bit_cast(float, u);
}
__device__ __forceinline__ float bflo(uint32_t v) {
    return __builtin_bit_cast(float, v << 16);
}
__device__ __forceinline__ float bfhi(uint32_t v) {
    return __builtin_bit_cast(float, v & 0xffff0000u);
}
__device__ __forceinline__ float sigm(float x) {
    return 1.f / (1.f + __expf(-x));
}

// async global->LDS, 16B per lane; LDS dest is wave-uniform base + lane*16
__device__ __forceinline__ void gload_lds16(const ushort_t* g, const ushort_t* l) {
    __builtin_amdgcn_global_load_lds(
        (const __attribute__((address_space(1))) void*)(uintptr_t)(g),
        (__attribute__((address_space(3))) void*)(uint32_t)(uintptr_t)(l),
        16, 0, 0);
}

// ---------------------------------------------------------------------------
// fp32 -> bf16 pre-convert of x, w1, w2
// ---------------------------------------------------------------------------
__global__ __launch_bounds__(256) void cvt_kernel(
    const float* __restrict__ x, const float* __restrict__ w1,
    const float* __restrict__ w2, ushort_t* __restrict__ xb,
    ushort_t* __restrict__ w1b, ushort_t* __restrict__ w2b) {
    const int i = (blockIdx.x * 256 + threadIdx.x) * 4;
    const float* s;
    ushort_t* d;
    if (i < NX) {
        s = x + i; d = xb + i;
    } else if (i < NX + NW1) {
        s = w1 + (i - NX); d = w1b + (i - NX);
    } else {
        s = w2 + (i - NX - NW1); d = w2b + (i - NX - NW1);
    }
    const float4 v = *(const float4*)s;
    us4 o;
    o.x = f2bf(v.x); o.y = f2bf(v.y); o.z = f2bf(v.z); o.w = f2bf(v.w);
    *(us4*)d = o;
}

// ---------------------------------------------------------------------------
// Shared fragment loader: [128 rows][64 k] LDS chunk, XOR-swizzled k-slots
// (LDS[row][slot] holds global k-slot slot^(row&7)); reads 4 frags x 2 slots.
// ---------------------------------------------------------------------------
__device__ __forceinline__ void lda4(bf16x8 (&af)[2][4], const ushort_t* c,
                                     int arow, int quad, int sw) {
#pragma unroll
    for (int s = 0; s < 2; ++s)
#pragma unroll
        for (int i = 0; i < 4; ++i)
            af[s][i] = *(const bf16x8*)&c[(arow + i * 16) * 64 +
                                          (((s * 4 + quad) ^ sw) << 3)];
}
__device__ __forceinline__ void ldb2(bf16x8 (&bfr)[2][2], const ushort_t* c,
                                     int bcol, int quad, int sw) {
#pragma unroll
    for (int s = 0; s < 2; ++s)
#pragma unroll
        for (int j = 0; j < 2; ++j)
            bfr[s][j] = *(const bf16x8*)&c[(bcol + j * 16) * 64 +
                                           (((s * 4 + quad) ^ sw) << 3)];
}
template <int QM, int QN>
__device__ __forceinline__ void mm16(f32x4 (&acc)[8][4],
                                     const bf16x8 (&af)[2][4],
                                     const bf16x8 (&bfr)[2][2]) {
#pragma unroll
    for (int s = 0; s < 2; ++s)
#pragma unroll
        for (int i = 0; i < 4; ++i)
#pragma unroll
            for (int j = 0; j < 2; ++j)
                acc[QM * 4 + i][QN * 2 + j] =
                    __builtin_amdgcn_mfma_f32_16x16x32_bf16(
                        af[s][i], bfr[s][j], acc[QM * 4 + i][QN * 2 + j], 0, 0, 0);
}

// ---------------------------------------------------------------------------
// GEMM1: 256x256 / BK=64 / 8-wave, ONE barrier per K-tile (R3, verified
// 101.5us / ~1016 TF, MfmaUtil 44%). Six K-loop structures tried (R1 8-phase,
// R2 3-phase-reg, R3 1-barrier, R8 BK=32 depth-3, R10 256x128 depth-3):
// R3 wins. 128KB LDS => 1 block/CU; the ~44% cap is the intra-window
// first-read drain. Do NOT restructure without new counter evidence.
// ---------------------------------------------------------------------------
template <bool OUT_BF16>
__global__ __launch_bounds__(512, 2) void gemm256(
    const ushort_t* __restrict__ A, const ushort_t* __restrict__ B,
    void* __restrict__ Cv, int M, int N, int K) {
    __shared__ __align__(16) ushort_t sA[2][2][8192];
    __shared__ __align__(16) ushort_t sB[2][2][8192];

    const int tid  = threadIdx.x;
    const int lane = tid & 63;
    const int wave = tid >> 6;   // 0..7
    const int wm   = wave >> 2;  // 0..1
    const int wn   = wave & 3;   // 0..3
    const int quad = lane >> 4;
    const int l15  = lane & 15;
    const int sw   = lane & 7;   // row&7 for fragment rows

    // bijective XCD swizzle (nwg % 8 == 0 for our shapes)
    int wg = blockIdx.x;
    const int nwg = gridDim.x;
    if ((nwg & 7) == 0) wg = (wg & 7) * (nwg >> 3) + (wg >> 3);
    const int nbx = N >> 8;
    const int bx = wg % nbx;
    const int by = wg / nbx;
    const long tm0 = (long)by << 8;
    const long tn0 = (long)bx << 8;

    const ushort_t* gA = A + (size_t)tm0 * K;
    const ushort_t* gB = B + (size_t)tn0 * K;

    // staging per-lane source offsets (elements), inverse-swizzled k-slot
    const int l8 = lane >> 3;                 // = dest row & 7
    const int ss = (lane & 7) ^ l8;           // source k-slot
    const uint32_t rA = (uint32_t)((wave & 3) * 16 + l8 + (wave >> 2) * 128);
    const int cB = wave * 16 + l8;            // chunk-local col (strip-safe)
    const uint32_t rB = (uint32_t)((cB >> 5) * 64 + (cB & 31));
    const uint32_t offA0 = rA * (uint32_t)K + (uint32_t)ss * 8u;
    const uint32_t offA1 = offA0 + 8u * (uint32_t)K;
    const uint32_t offB0 = rB * (uint32_t)K + (uint32_t)ss * 8u;
    const uint32_t offB1 = offB0 + 8u * (uint32_t)K;

    const auto stA = [&](int tt, int q) {
        ushort_t* d = &sA[tt & 1][q][wave << 10];
        const size_t ko = (size_t)tt * 64 + (size_t)q * 64 * (size_t)K;
        gload_lds16(gA + ko + offA0, d);
        gload_lds16(gA + ko + offA1, d + 512);
    };
    const auto stB = [&](int tt, int q) {
        ushort_t* d = &sB[tt & 1][q][wave << 10];
        const size_t ko = (size_t)tt * 64 + (size_t)q * 32 * (size_t)K;
        gload_lds16(gB + ko + offB0, d);
        gload_lds16(gB + ko + offB1, d + 512);
    };

    const int arow = wm * 64 + l15;
    const int bcol = wn * 32 + l15;

    f32x4 acc[8][4] = {};
    bf16x8 af0[2][4], af1[2][4], bf0[2][2], bf1[2][2];

    const int NT = K >> 6;  // K-tiles

    // prologue: stage tile 0 fully, drain, barrier.
    stA(0, 0); stB(0, 0); stB(0, 1); stA(0, 1);
    asm volatile("s_waitcnt vmcnt(0)" ::: "memory");
    __builtin_amdgcn_s_barrier();

    for (int T = 0; T < NT; ++T) {
        const int cur = T & 1;
        const ushort_t* a0 = &sA[cur][0][0];
        const ushort_t* a1 = &sA[cur][1][0];
        const ushort_t* b0 = &sB[cur][0][0];
        const ushort_t* b1 = &sB[cur][1][0];
        const bool st1 = (T + 1 < NT);

        // all 24 ds_reads first (operand waits can never alias staging)
        lda4(af0, a0, arow, quad, sw);
        ldb2(bf0, b0, bcol, quad, sw);
        ldb2(bf1, b1, bcol, quad, sw);
        lda4(af1, a1, arow, quad, sw);
        // all 8 stages for tile T+1 into the other (dead) buffer
        if (st1) {
            stA(T + 1, 0); stB(T + 1, 0);
            stB(T + 1, 1); stA(T + 1, 1);
        }
        // 64 MFMA; compiler waits lgkm counted per operand cluster, so
        // reads 13..24 land under mm<0,0>'s execution.
        __builtin_amdgcn_s_setprio(1);
        mm16<0, 0>(acc, af0, bf0);
        mm16<0, 1>(acc, af0, bf1);
        mm16<1, 0>(acc, af1, bf0);
        mm16<1, 1>(acc, af1, bf1);
        __builtin_amdgcn_s_setprio(0);
        // drain this tile's stages (issued ~one MFMA-cluster ago => stale)
        if (st1) asm volatile("s_waitcnt vmcnt(0)" ::: "memory");
        __builtin_amdgcn_s_barrier();
    }

    // epilogue: C/D layout col=lane&15, row=quad*4+reg
#pragma unroll
    for (int ai = 0; ai < 8; ++ai) {
        const long row0 = tm0 + wm * 128 + (ai >> 2) * 64 + (ai & 3) * 16 + quad * 4;
#pragma unroll
        for (int bj = 0; bj < 4; ++bj) {
            const long col = tn0 + wn * 64 + (bj >> 1) * 32 + (bj & 1) * 16 + l15;
#pragma unroll
            for (int r = 0; r < 4; ++r) {
                if constexpr (OUT_BF16) {
                    ((ushort_t*)Cv)[(size_t)(row0 + r) * N + col] = f2bf(acc[ai][bj][r]);
                } else {
                    ((float*)Cv)[(size_t)(row0 + r) * N + col] = acc[ai][bj][r];
                }
            }
        }
    }
}

// ---------------------------------------------------------------------------
// GEMM2: 256(M)x128(N) / BK=64 / 8-wave, triple-buffered, counted vmcnt(6),
// 2-tile prefetch (R7, best-verified GEMM2). R9's 128^2/2-block variant
// regressed +13us (more staging traffic, no cross-block overlap) — reverted.
// ---------------------------------------------------------------------------
__global__ __launch_bounds__(512, 1) void gemm_mn(
    const ushort_t* __restrict__ A, const ushort_t* __restrict__ B,
    float* __restrict__ C, int M, int N, int K) {
    __shared__ __align__(16) ushort_t sA[3][2][8192];
    __shared__ __align__(16) ushort_t sB[3][8192];

    const int tid  = threadIdx.x;
    const int lane = tid & 63;
    const int wave = tid >> 6;   // 0..7
    const int wm   = wave >> 1;  // 0..3
    const int wn   = wave & 1;   // 0..1
    const int quad = lane >> 4;
    const int l15  = lane & 15;
    const int sw   = lane & 7;

    // bijective XCD swizzle (256 % 8 == 0)
    int wg = blockIdx.x;
    const int nwg = gridDim.x;
    if ((nwg & 7) == 0) wg = (wg & 7) * (nwg >> 3) + (wg >> 3);
    const int nbx = N >> 7;      // 128-col tiles
    const int bx = wg % nbx;
    const int by = wg / nbx;
    const long tm0 = (long)by << 8;   // 256-row tiles
    const long tn0 = (long)bx << 7;

    const ushort_t* gA = A + (size_t)tm0 * K;
    const ushort_t* gB = B + (size_t)tn0 * K;

    const int l8 = lane >> 3;
    const int ss = (lane & 7) ^ l8;
    const uint32_t rA = (uint32_t)((wave & 3) * 16 + l8 + (wave >> 2) * 128);
    const uint32_t rB = (uint32_t)(wave * 16 + l8);
    const uint32_t offA0 = rA * (uint32_t)K + (uint32_t)ss * 8u;
    const uint32_t offA1 = offA0 + 8u * (uint32_t)K;
    const uint32_t offB0 = rB * (uint32_t)K + (uint32_t)ss * 8u;
    const uint32_t offB1 = offB0 + 8u * (uint32_t)K;

    const auto stA = [&](int tt, int q) {
        ushort_t* d = &sA[tt % 3][q][wave << 10];
        const size_t ko = (size_t)tt * 64 + (size_t)q * 64 * (size_t)K;
        gload_lds16(gA + ko + offA0, d);
        gload_lds16(gA + ko + offA1, d + 512);
    };
    const auto stB = [&](int tt) {
        ushort_t* d = &sB[tt % 3][wave << 10];
        const size_t ko = (size_t)tt * 64;
        gload_lds16(gB + ko + offB0, d);
        gload_lds16(gB + ko + offB1, d + 512);
    };

    const int cq   = wm & 1;                  // this wave's A chunk
    const int arow = (wm >> 1) * 64 + l15;    // local row base in chunk
    const int bcol = wn * 64 + l15;

    f32x4 acc[4][4] = {};
    bf16x8 af[2][4], bf[2][4];

    const int NT = K >> 6;  // 32 tiles

    stA(0, 0); stA(0, 1); stB(0);
    stA(1, 0); stA(1, 1); stB(1);
    asm volatile("s_waitcnt vmcnt(6)" ::: "memory");
    __builtin_amdgcn_s_barrier();

    for (int T = 0; T < NT; ++T) {
        const int cur = T % 3;
        const ushort_t* pa = &sA[cur][cq][0];
        const ushort_t* pb = &sB[cur][0];
        const bool st2 = (T + 2 < NT);

        lda4(af, pa, arow, quad, sw);
        lda4(bf, pb, bcol, quad, sw);
        if (st2) { stA(T + 2, 0); stA(T + 2, 1); stB(T + 2); }
        __builtin_amdgcn_s_setprio(1);
#pragma unroll
        for (int s = 0; s < 2; ++s)
#pragma unroll
            for (int i = 0; i < 4; ++i)
#pragma unroll
                for (int j = 0; j < 4; ++j)
                    acc[i][j] = __builtin_amdgcn_mfma_f32_16x16x32_bf16(
                        af[s][i], bf[s][j], acc[i][j], 0, 0, 0);
        __builtin_amdgcn_s_setprio(0);
        if (st2)                asm volatile("s_waitcnt vmcnt(6)" ::: "memory");
        else if (T + 1 < NT)    asm volatile("s_waitcnt vmcnt(0)" ::: "memory");
        __builtin_amdgcn_s_barrier();
    }

#pragma unroll
    for (int i = 0; i < 4; ++i) {
        const long row0 = tm0 + wm * 64 + i * 16 + quad * 4;
#pragma unroll
        for (int j = 0; j < 4; ++j) {
            const long col = tn0 + wn * 64 + j * 16 + l15;
#pragma unroll
            for (int r = 0; r < 4; ++r)
                C[(size_t)(row0 + r) * N + col] = acc[i][j][r];
        }
    }
}

// ---------------------------------------------------------------------------
// Segmented scan, 3 kernels (SEG=64, 4 blocks/CU — R7, verified; SEG sweep
// {32,64,128} -> {299,292,303} us total: 64 is the minimum).
// NOTE: do NOT hold the streams in large register arrays across phases —
// the compiler demotes >~32-dword locals to scratch. Re-read via L3.
// ---------------------------------------------------------------------------
__global__ __launch_bounds__(256) void scan_part1(
    const ushort_t* __restrict__ y, const float* __restrict__ cw,
    float* __restrict__ Ag, float* __restrict__ Bg) {
    const int gid = blockIdx.x * 256 + threadIdx.x;
    const int ch  = (gid & 1023) * 2;
    const int bs  = gid >> 10;          // [0, BATCH*SEG)
    const int b   = bs >> 6;
    const int seg = bs & 63;
    const int t0  = seg * SLEN;
    const size_t rowbase = (size_t)b * SEQ;
    const ushort_t* yz = y + 2048 + ch;
    const ushort_t* yh = y + 4096 + ch;

    float w[2][4];
#pragma unroll
    for (int c = 0; c < 2; ++c)
#pragma unroll
        for (int k = 0; k < 4; ++k) w[c][k] = cw[(ch + c) * 4 + k];

    auto ld2 = [&](const ushort_t* p, int t) -> uint32_t {
        return *(const uint32_t*)(p + (rowbase + (size_t)t) * 6144);
    };
    auto zpair = [&](int t, float* out) {
        if (t < 0) { out[0] = 0.f; out[1] = 0.f; }
        else { uint32_t v = ld2(yz, t); out[0] = bflo(v); out[1] = bfhi(v); }
    };

    float z1[2], z2[2], z3[2], A[2] = {1.f, 1.f}, Bv[2] = {0.f, 0.f};
    zpair(t0 - 1, z1); zpair(t0 - 2, z2); zpair(t0 - 3, z3);

#pragma unroll 8
    for (int t = t0; t < t0 + SLEN; ++t) {
        const uint32_t vz = ld2(yz, t);
        const uint32_t vh = ld2(yh, t);
        const float zr[2] = {bflo(vz), bfhi(vz)};
        const float hr[2] = {bflo(vh), bfhi(vh)};
#pragma unroll
        for (int c = 0; c < 2; ++c) {
            const float cv = w[c][0] * z3[c] + w[c][1] * z2[c] +
                             w[c][2] * z1[c] + w[c][3] * zr[c];
            const float s = sigm(cv);
            z3[c] = z2[c]; z2[c] = z1[c]; z1[c] = zr[c];
            const float a = 1.f - s;
            A[c] *= a;
            Bv[c] = a * Bv[c] + s * hr[c];
        }
    }
    const size_t idx = ((size_t)b * SEG + seg) * HID + ch;
    *(float2*)&Ag[idx] = make_float2(A[0], A[1]);
    *(float2*)&Bg[idx] = make_float2(Bv[0], Bv[1]);
}

// one thread per (b, ch): serial exclusive combine over SEG segments
__global__ __launch_bounds__(256) void scan_part2(
    const float* __restrict__ Ag, const float* __restrict__ Bg,
    float* __restrict__ Cr) {
    const int gid = blockIdx.x * 256 + threadIdx.x;  // [0, 8192)
    const int b  = gid >> 11;
    const int ch = gid & 2047;
    float carry = 0.f;
#pragma unroll
    for (int s = 0; s < SEG; ++s) {
        const size_t idx = ((size_t)b * SEG + s) * HID + ch;
        Cr[idx] = carry;
        carry = Ag[idx] * carry + Bg[idx];
    }
}

__global__ __launch_bounds__(256) void scan_part3(
    const ushort_t* __restrict__ y, const float* __restrict__ cw,
    const float* __restrict__ Cr, ushort_t* __restrict__ u) {
    const int gid = blockIdx.x * 256 + threadIdx.x;
    const int ch  = (gid & 1023) * 2;
    const int bs  = gid >> 10;
    const int b   = bs >> 6;
    const int seg = bs & 63;
    const int t0  = seg * SLEN;
    const size_t rowbase = (size_t)b * SEQ;
    const ushort_t* yo = y + ch;
    const ushort_t* yz = y + 2048 + ch;
    const ushort_t* yh = y + 4096 + ch;

    float w[2][4];
#pragma unroll
    for (int c = 0; c < 2; ++c)
#pragma unroll
        for (int k = 0; k < 4; ++k) w[c][k] = cw[(ch + c) * 4 + k];

    auto ld2 = [&](const ushort_t* p, int t) -> uint32_t {
        return *(const uint32_t*)(p + (rowbase + (size_t)t) * 6144);
    };
    auto zpair = [&](int t, float* out) {
        if (t < 0) { out[0] = 0.f; out[1] = 0.f; }
        else { uint32_t v = ld2(yz, t); out[0] = bflo(v); out[1] = bfhi(v); }
    };

    const size_t cidx = ((size_t)b * SEG + seg) * HID + ch;
    float h[2] = {Cr[cidx], Cr[cidx + 1]};
    float z1[2], z2[2], z3[2];
    zpair(t0 - 1, z1); zpair(t0 - 2, z2); zpair(t0 - 3, z3);

#pragma unroll 8
    for (int t = t0; t < t0 + SLEN; ++t) {
        const uint32_t vz = ld2(yz, t);
        const uint32_t vh = ld2(yh, t);
        const uint32_t vo = ld2(yo, t);
        const float zr[2] = {bflo(vz), bfhi(vz)};
        const float hr[2] = {bflo(vh), bfhi(vh)};
        const float o1[2] = {bflo(vo), bfhi(vo)};
        ushort_t res[2];
#pragma unroll
        for (int c = 0; c < 2; ++c) {
            const float cv = w[c][0] * z3[c] + w[c][1] * z2[c] +
                             w[c][2] * z1[c] + w[c][3] * zr[c];
            const float s = sigm(cv);
            z3[c] = z2[c]; z2[c] = z1[c]; z1[c] = zr[c];
            h[c] = (1.f - s) * h[c] + s * hr[c];
            const float sil = o1[c] * sigm(o1[c]);
            res[c] = f2bf(sil * h[c]);
        }
        *(uint32_t*)&u[(rowbase + (size_t)t) * (size_t)HID + ch] =
            (uint32_t)res[0] | ((uint32_t)res[1] << 16);
    }
}

// ---------------------------------------------------------------------------
extern "C" void kernel_launch(void* const* d_in, const int* in_sizes, int n_in,
                              void* d_out, int out_size, void* d_ws, size_t ws_size,
                              hipStream_t stream) {
    const float* x  = (const float*)d_in[0];
    const float* w1 = (const float*)d_in[1];
    const float* w2 = (const float*)d_in[2];
    const float* cw = (const float*)d_in[3];
    char* ws = (char*)d_ws;

    // ws layout (bytes): xb 16MiB | w1b 12MiB | w2b 4MiB | y 96MiB | u 32MiB = 160MiB
    ushort_t* xb  = (ushort_t*)(ws);
    ushort_t* w1b = (ushort_t*)(ws + (size_t)16777216);
    ushort_t* w2b = (ushort_t*)(ws + (size_t)29360128);
    ushort_t* y   = (ushort_t*)(ws + (size_t)33554432);
    ushort_t* u   = (ushort_t*)(ws + (size_t)134217728);
    // scan scratch reuses the xb region (dead after GEMM1): 3 x 2 MiB fp32
    float* Ag = (float*)(ws);
    float* Bg = (float*)(ws + (size_t)2097152);
    float* Cr = (float*)(ws + (size_t)4194304);
    float* out = (float*)d_out;

    cvt_kernel<<<16384, 256, 0, stream>>>(x, w1, w2, xb, w1b, w2b);
    // GEMM1: 256^2 single-barrier de-phased kernel (R3), grid = 32*24 = 768
    gemm256<true><<<dim3(768), 512, 0, stream>>>(xb, w1b, (void*)y, MROWS, N1, K1);
    // scans at SEG=64: 1024 blocks = 4 blocks/CU
    scan_part1<<<1024, 256, 0, stream>>>(y, cw, Ag, Bg);
    scan_part2<<<32, 256, 0, stream>>>(Ag, Bg, Cr);
    scan_part3<<<1024, 256, 0, stream>>>(y, cw, Cr, u);
    // GEMM2: 256x128-tile triple-buffered kernel (R7), grid = 32*8 = 256
    gemm_mn<<<dim3(256), 512, 0, stream>>>(u, w2b, out, MROWS, N2, K2);
}